// Round 7
// baseline (144.726 us; speedup 1.0000x reference)
//
#include <hip/hip_runtime.h>
#include <stdint.h>

#define SEQ  2048
#define DIMC 256
#define HID  512
#define NH   8
#define DH   64

typedef __attribute__((ext_vector_type(8))) short bf16x8;
typedef __attribute__((ext_vector_type(4))) float f32x4;
typedef __attribute__((ext_vector_type(16))) float f32x16;
typedef __attribute__((ext_vector_type(2))) unsigned uint2v;
typedef __attribute__((address_space(1))) const uint32_t guint_t;
typedef __attribute__((address_space(3))) uint32_t luint_t;

// async global->LDS, 16B per lane; LDS dest = wave-uniform base + lane*16
__device__ __forceinline__ void gld16(const void* g, void* l) {
  __builtin_amdgcn_global_load_lds((guint_t*)g, (luint_t*)l, 16, 0, 0);
}

// raw barrier: no compiler-inserted vmcnt(0) drain (unlike __syncthreads)
__device__ __forceinline__ void barrier_raw() {
  asm volatile("" ::: "memory");
  __builtin_amdgcn_s_barrier();
  asm volatile("" ::: "memory");
}
#define WAITVM(n) asm volatile("s_waitcnt vmcnt(" #n ")" ::: "memory")

__device__ __forceinline__ unsigned short f2bf(float f) {
  union { float f; uint32_t u; } v; v.f = f;
  return (unsigned short)((v.u + 0x7FFFu + ((v.u >> 16) & 1u)) >> 16);
}

__device__ __forceinline__ uint32_t fbits(float f) {
  union { float f; uint32_t u; } v; v.f = f; return v.u;
}
__device__ __forceinline__ float ffrombits(uint32_t u) {
  union { uint32_t u; float f; } v; v.u = u; return v.f;
}

// pack two fp32 -> (bf16,bf16) dword in ONE instr (RNE)
__device__ __forceinline__ uint32_t cvtpk(float a, float b) {
  uint32_t r;
  asm("v_cvt_pk_bf16_f32 %0, %1, %2" : "=v"(r) : "v"(a), "v"(b));
  return r;
}

// exchange hi 32 lanes of a with lo 32 lanes of b
__device__ __forceinline__ void swap32(uint32_t& a, uint32_t& b) {
#if __has_builtin(__builtin_amdgcn_permlane32_swap)
  uint2v r = __builtin_amdgcn_permlane32_swap(a, b, false, false);
  a = r[0]; b = r[1];
#else
  uint32_t aw = __shfl_xor(a, 32);
  uint32_t bw = __shfl_xor(b, 32);
  bool lo = (threadIdx.x & 32) == 0;
  uint32_t an = lo ? a : bw;
  uint32_t bn = lo ? aw : b;
  a = an; b = bn;
#endif
}

// ---------------------------------------------------------------------------
// prep: w_qkv -> bf16 (Q rows pre-scaled by SCALE*log2e), w_out -> bf16,
//       x [b][i][n] fp32 -> xT [b][n][i] bf16
// ---------------------------------------------------------------------------
__global__ __launch_bounds__(256) void prep_kernel(
    const float* __restrict__ x, const float* __restrict__ wqkv,
    const float* __restrict__ wout,
    unsigned short* __restrict__ wqkv_b, unsigned short* __restrict__ wout_b,
    unsigned short* __restrict__ xT) {
  __shared__ float tile[64][65];
  int blk = blockIdx.x;
  int t = threadIdx.x;
  if (blk < 384) {
    int idx = blk * 1024 + t * 4;
    float4 v = *(const float4*)(wqkv + idx);
    float s = ((idx >> 8) < HID) ? 0.18033688011112042f : 1.0f;  // 0.125*log2(e)
    ushort4 o;
    o.x = f2bf(v.x * s); o.y = f2bf(v.y * s);
    o.z = f2bf(v.z * s); o.w = f2bf(v.w * s);
    *(ushort4*)(wqkv_b + idx) = o;
    return;
  }
  if (blk < 512) {
    int idx = (blk - 384) * 1024 + t * 4;
    float4 v = *(const float4*)(wout + idx);
    ushort4 o;
    o.x = f2bf(v.x); o.y = f2bf(v.y); o.z = f2bf(v.z); o.w = f2bf(v.w);
    *(ushort4*)(wout_b + idx) = o;
    return;
  }
  int tid = blk - 512;
  int b  = tid >> 7;
  int r  = tid & 127;
  int i0 = (r >> 5) * 64;
  int n0 = (r & 31) * 64;
  const float* xb = x + (size_t)b * DIMC * SEQ;
  int tn = t & 15, ti = t >> 4;
#pragma unroll
  for (int j = 0; j < 4; j++) {
    int il = ti + j * 16;
    float4 v = *(const float4*)(xb + (size_t)(i0 + il) * SEQ + n0 + tn * 4);
    tile[il][tn*4+0] = v.x; tile[il][tn*4+1] = v.y;
    tile[il][tn*4+2] = v.z; tile[il][tn*4+3] = v.w;
  }
  __syncthreads();
  unsigned short* xTb = xT + (size_t)b * SEQ * DIMC;
#pragma unroll
  for (int j = 0; j < 4; j++) {
    int nl = ti + j * 16;
    int i4 = tn * 4;
    uint2 pk;
    pk.x = (uint32_t)f2bf(tile[i4+0][nl]) | ((uint32_t)f2bf(tile[i4+1][nl]) << 16);
    pk.y = (uint32_t)f2bf(tile[i4+2][nl]) | ((uint32_t)f2bf(tile[i4+3][nl]) << 16);
    *(uint2*)(xTb + (size_t)(n0 + nl) * DIMC + i0 + i4) = pk;
  }
}

// ---------------------------------------------------------------------------
// qkv_gemm: [1536,256]x[256,2048] per batch, 128x128 tile, BK=64.
// XCD-pinned swizzle; double-buffered gld16; one barrier/K-step.
// ---------------------------------------------------------------------------
__global__ __launch_bounds__(256, 3) void qkv_gemm(
    const unsigned short* __restrict__ wq, const unsigned short* __restrict__ xT,
    unsigned short* __restrict__ Qs, unsigned short* __restrict__ Ks,
    unsigned short* __restrict__ Vt) {
  __shared__ unsigned short lds[32768];
  int id = blockIdx.x + 12 * blockIdx.y + 192 * blockIdx.z;  // flat [0,768)
  int xcd = id & 7, wg = id >> 3;          // wg in [0,96)
  int pair = xcd * 8 + wg / 12;            // [0,64) = (n0idx, b)
  int o0 = (wg % 12) * 128;
  int n0 = (pair & 15) * 128;
  int b  = pair >> 4;
  int t  = threadIdx.x;
  int wv = t >> 6, l = t & 63, l15 = l & 15, q = l >> 4;
  int wm = (wv & 1) * 64, wn = (wv >> 1) * 64;
  f32x4 acc[4][4];
#pragma unroll
  for (int i = 0; i < 4; i++)
#pragma unroll
    for (int j = 0; j < 4; j++) acc[i][j] = (f32x4){0.f, 0.f, 0.f, 0.f};
  const unsigned short* Ag = wq + (size_t)o0 * DIMC;
  const unsigned short* Bg = xT + ((size_t)b * SEQ + n0) * DIMC;
  int lrow8 = l >> 3, lcol = l & 7;

  auto stage = [&](int kk, int buf) {
    unsigned short* la = lds + (buf << 14);
    unsigned short* lb = la + 8192;
    int k0 = kk * 64;
#pragma unroll
    for (int c0 = 0; c0 < 4; c0++) {
      int c = wv * 4 + c0;
      int row = c * 8 + lrow8;
      int sg = lcol ^ (row & 7);
      gld16(Ag + (size_t)row * DIMC + k0 + sg * 8, la + c * 512);
      gld16(Bg + (size_t)row * DIMC + k0 + sg * 8, lb + c * 512);
    }
  };

  stage(0, 0);
  for (int kk = 0; kk < 4; kk++) {
    int cur = kk & 1;
    WAITVM(0);                             // own stage(kk) loads landed
    barrier_raw();                         // => all waves' stage(kk) landed
    if (kk < 3) stage(kk + 1, cur ^ 1);    // WAR-safe after barrier
    unsigned short* la = lds + (cur << 14);
    unsigned short* lb = la + 8192;
#pragma unroll
    for (int kh = 0; kh < 2; kh++) {
      bf16x8 af[4], bfr[4];
#pragma unroll
      for (int mt = 0; mt < 4; mt++) {
        int row = wm + mt*16 + l15;
        af[mt] = *(const bf16x8*)(la + row*64 + ((kh*4 + q) ^ (row & 7)) * 8);
      }
#pragma unroll
      for (int nt = 0; nt < 4; nt++) {
        int row = wn + nt*16 + l15;
        bfr[nt] = *(const bf16x8*)(lb + row*64 + ((kh*4 + q) ^ (row & 7)) * 8);
      }
#pragma unroll
      for (int mt = 0; mt < 4; mt++)
#pragma unroll
        for (int nt = 0; nt < 4; nt++)
          acc[mt][nt] = __builtin_amdgcn_mfma_f32_16x16x32_bf16(af[mt], bfr[nt], acc[mt][nt], 0, 0, 0);
    }
  }
  barrier_raw();                 // all waves done with LDS buffers before reuse
  int seg3 = o0 >> 9;            // 0=Q, 1=K, 2=V
  int h0   = (o0 & 511) >> 6;
  if (seg3 == 2) {
    // V: transpose via LDS [ol][nn] -> 16B n-contiguous stores
#pragma unroll
    for (int mt = 0; mt < 4; mt++)
#pragma unroll
      for (int nt = 0; nt < 4; nt++)
#pragma unroll
        for (int r = 0; r < 4; r++) {
          int ol = wm + mt * 16 + q * 4 + r;
          int nn = wn + nt * 16 + l15;
          lds[ol * 136 + nn] = f2bf(acc[mt][nt][r]);
        }
    __syncthreads();
#pragma unroll
    for (int i = 0; i < 8; i++) {
      int idx = i * 256 + t;
      int ol  = idx >> 4;
      int nnb = (idx & 15) * 8;
      uint4 v = *(const uint4*)(lds + ol * 136 + nnb);
      int h = h0 + (ol >> 6), d = ol & 63;
      *(uint4*)(Vt + (((size_t)b * NH + h) * DH + d) * SEQ + n0 + nnb) = v;
    }
  } else {
    unsigned short* dst = (seg3 == 0) ? Qs : Ks;
#pragma unroll
    for (int mt = 0; mt < 4; mt++)
#pragma unroll
      for (int nt = 0; nt < 4; nt++)
#pragma unroll
        for (int r = 0; r < 4; r++) {
          int ol = wm + mt * 16 + q * 4 + r;
          int nn = wn + nt * 16 + l15;
          lds[nn * 136 + ol] = f2bf(acc[mt][nt][r]);
        }
    __syncthreads();
#pragma unroll
    for (int i = 0; i < 8; i++) {
      int idx = i * 256 + t;
      int nn  = idx >> 4;
      int olb = (idx & 15) * 8;
      uint4 v = *(const uint4*)(lds + nn * 136 + olb);
      int h = h0 + (olb >> 6), d = olb & 63;
      *(uint4*)(dst + (((size_t)b * NH + h) * SEQ + n0 + nn) * DH + d) = v;
    }
  }
}

// ---------------------------------------------------------------------------
// attn: BARRIER-FREE main loop. 1024 XCD-swizzled blocks x 4 waves, 2 blk/CU.
// Wave w owns keys [w*512, w*512+512) (kv-split-4) and processes ALL 64
// queries of the block's q-tile (2 q-groups/wave; K/V frags shared across
// both). K/V staged into the wave's PRIVATE 16KB LDS quarter by its own
// gld16s, 2-deep pipeline synced only by counted vmcnt(8) -- no s_barrier
// in the loop (r6 showed ~2200 of 3840 cyc/iter was barrier-lockstep stall;
// pipe work is ~1600, dominated by quarter-rate exp2). Epilogue: 4-way
// additive combine via LDS (barriers only there).
// ---------------------------------------------------------------------------
__global__ __launch_bounds__(256, 2) void attn_kernel(
    const unsigned short* __restrict__ Qs, const unsigned short* __restrict__ Ks,
    const unsigned short* __restrict__ Vt, unsigned short* __restrict__ AO) {
  __shared__ unsigned short KVs[32768];  // [wave][2 buf][K 2048 | V 2048] shorts = 64KB
  __shared__ float Lc[256];              // [wave][64 q] row-sum partials
  // XCD swizzle: id&7 = XCD slot; 4 bh x 32 q-tiles per XCD -> K/V L2-resident
  int id = blockIdx.x;
  int s  = id >> 3;
  int bh = (id & 7) * 4 + (s & 3);
  int q0 = (s >> 2) * 64;
  int b = bh >> 3, h = bh & 7;
  int t = threadIdx.x;
  int w = t >> 6, l = t & 63, l31 = l & 31, lh = l >> 5;

  // Q B-frags for BOTH 32-q groups (n=query=l31, k=head-dim)
  const unsigned short* Qg = Qs + ((size_t)bh * SEQ + q0) * DH;
  bf16x8 qb[2][4];
#pragma unroll
  for (int qt = 0; qt < 2; qt++)
#pragma unroll
    for (int kc = 0; kc < 4; kc++)
      qb[qt][kc] = *(const bf16x8*)(Qg + (qt*32 + l31) * DH + kc*16 + lh*8);

  f32x16 oacc[2][2];
  float lsum0 = 0.f, lsum1 = 0.f;
#pragma unroll
  for (int qt = 0; qt < 2; qt++)
#pragma unroll
    for (int dt = 0; dt < 2; dt++)
#pragma unroll
      for (int r = 0; r < 16; r++) oacc[qt][dt][r] = 0.f;

  // wave-private KV chunk: keys [w*512, w*512+512)
  const unsigned short* Ksrc = Ks + ((size_t)bh * SEQ + w * 512) * DH;
  const unsigned short* Vsrc = Vt + (size_t)bh * DH * SEQ + w * 512;
  int l3 = l >> 3, l7 = l & 7;
  int u  = l7 ^ (l3 & 7);                  // V paired-row swizzle (r&7 == l3&7, g-invariant)
  const unsigned short* Kg0 = Ksrc + (size_t)l3 * DH + u * 8;
  const unsigned short* Vg0 = Vsrc + (size_t)((u >> 2) * 32 + l3) * SEQ + (u & 3) * 8;
  unsigned short* myK = (unsigned short*)KVs + w * 8192;

  auto stage = [&](int it2, int buf) {
    const unsigned short* kp = Kg0 + (size_t)it2 * 32 * DH;
    const unsigned short* vp = Vg0 + it2 * 32;
    unsigned short* kd = myK + buf * 4096;
    unsigned short* vd = kd + 2048;
#pragma unroll
    for (int g = 0; g < 4; g++) {
      gld16(kp + g * 8 * DH, kd + g * 512);
      gld16(vp + (size_t)g * 8 * SEQ, vd + g * 512);
    }
  };

  stage(0, 0);
  stage(1, 1);
  for (int it = 0; it < 16; it++) {
    int buf = it & 1;
    if (it == 15) { WAITVM(0); } else { WAITVM(8); }  // own stage(it) landed; stage(it+1) in flight
    const unsigned short* Kst = myK + buf * 4096;
    const unsigned short* Vst = Kst + 2048;
    // S^T = K Q^T for both q-groups; K frag shared
    f32x16 st[2];
#pragma unroll
    for (int qt = 0; qt < 2; qt++)
#pragma unroll
      for (int r = 0; r < 16; r++) st[qt][r] = 0.f;
    __builtin_amdgcn_s_setprio(1);
#pragma unroll
    for (int kc = 0; kc < 4; kc++) {
      bf16x8 kf = *(const bf16x8*)(Kst + l31 * 64 + ((kc*2 + lh) ^ (l31 & 7)) * 8);
      st[0] = __builtin_amdgcn_mfma_f32_32x32x16_bf16(kf, qb[0][kc], st[0], 0, 0, 0);
      st[1] = __builtin_amdgcn_mfma_f32_32x32x16_bf16(kf, qb[1][kc], st[1], 0, 0, 0);
    }
    __builtin_amdgcn_s_setprio(0);
    // V B-frags (n=d, k=key 32), shared across q-groups
    bf16x8 vf[2][2];
#pragma unroll
    for (int kc2 = 0; kc2 < 2; kc2++)
#pragma unroll
      for (int dt = 0; dt < 2; dt++)
        vf[kc2][dt] = *(const bf16x8*)(Vst + l31 * 64 +
                                       ((dt*4 + kc2*2 + lh) ^ (l31 & 7)) * 8);
#pragma unroll
    for (int qt = 0; qt < 2; qt++) {
      float p[16];
#pragma unroll
      for (int r = 0; r < 16; r++) p[r] = __builtin_amdgcn_exp2f(st[qt][r]);
      {
        float t0=p[0]+p[1],  t1=p[2]+p[3],  t2=p[4]+p[5],   t3=p[6]+p[7];
        float t4=p[8]+p[9],  t5=p[10]+p[11], t6=p[12]+p[13], t7=p[14]+p[15];
        float a = ((t0+t1)+(t2+t3)) + ((t4+t5)+(t6+t7));
        if (qt == 0) lsum0 += a; else lsum1 += a;
      }
      // D-layout -> A-layout in registers (permlane32_swap + cvt_pk_bf16)
      bf16x8 af[2];
#pragma unroll
      for (int hf = 0; hf < 2; hf++) {
        uint32_t xs[4], ys[4];
#pragma unroll
        for (int j = 0; j < 4; j++) {
          xs[j] = fbits(p[hf*8 + j]);
          ys[j] = fbits(p[hf*8 + 4 + j]);
          swap32(xs[j], ys[j]);
        }
        union { uint32_t u[4]; bf16x8 v; } cv;
        cv.u[0] = cvtpk(ffrombits(xs[0]), ffrombits(xs[1]));
        cv.u[1] = cvtpk(ffrombits(xs[2]), ffrombits(xs[3]));
        cv.u[2] = cvtpk(ffrombits(ys[0]), ffrombits(ys[1]));
        cv.u[3] = cvtpk(ffrombits(ys[2]), ffrombits(ys[3]));
        af[hf] = cv.v;
      }
      __builtin_amdgcn_s_setprio(1);
#pragma unroll
      for (int kc2 = 0; kc2 < 2; kc2++)
#pragma unroll
        for (int dt = 0; dt < 2; dt++)
          oacc[qt][dt] = __builtin_amdgcn_mfma_f32_32x32x16_bf16(af[kc2], vf[kc2][dt], oacc[qt][dt], 0, 0, 0);
      __builtin_amdgcn_s_setprio(0);
    }
    if (it < 14) {
      asm volatile("s_waitcnt lgkmcnt(0)" ::: "memory");  // buf's ds_reads done (WAR)
      stage(it + 2, buf);
    }
  }
  // ---- 4-way additive combine (disjoint key chunks; no max-rescale) ----
  lsum0 += __shfl_xor(lsum0, 32);          // lo/hi halves hold disjoint keys
  lsum1 += __shfl_xor(lsum1, 32);
  if (l < 32) { Lc[w*64 + l31] = lsum0; Lc[w*64 + 32 + l31] = lsum1; }
  __syncthreads();
  float* Ob = (float*)KVs;                 // 3 x [64q][64d] fp32 partials = 48 KB
  if (w > 0) {
    float* Ow = Ob + (w - 1) * 4096;
#pragma unroll
    for (int qt = 0; qt < 2; qt++)
#pragma unroll
      for (int dt = 0; dt < 2; dt++)
#pragma unroll
        for (int r = 0; r < 16; r++) {
          int qrow = qt*32 + (r & 3) + 8*(r >> 2) + 4*lh;
          Ow[qrow * 64 + dt*32 + l31] = oacc[qt][dt][r];
        }
  }
  __syncthreads();
  if (w == 0) {
    unsigned short* AOb = AO + (size_t)b * SEQ * HID + h * DH;
#pragma unroll
    for (int qt = 0; qt < 2; qt++)
#pragma unroll
      for (int r = 0; r < 16; r++) {
        int qrow = qt*32 + (r & 3) + 8*(r >> 2) + 4*lh;
        float inv = __builtin_amdgcn_rcpf(Lc[qrow] + Lc[64 + qrow] +
                                          Lc[128 + qrow] + Lc[192 + qrow]);
        int n = q0 + qrow;
#pragma unroll
        for (int dt = 0; dt < 2; dt++) {
          int idx = qrow * 64 + dt*32 + l31;
          float val = (oacc[qt][dt][r] + Ob[idx] + Ob[4096 + idx] + Ob[8192 + idx]) * inv;
          AOb[(size_t)n * HID + dt*32 + l31] = f2bf(val);
        }
      }
  }
}

// ---------------------------------------------------------------------------
// out_gemm: [256,512] x AO^T -> out[b][256][2048] fp32 + bias, 64x64 tile.
// XCD-pinned swizzle; double-buffered gld16; one barrier/K-step.
// ---------------------------------------------------------------------------
__global__ __launch_bounds__(256, 2) void out_gemm(
    const unsigned short* __restrict__ wo, const unsigned short* __restrict__ AO,
    const float* __restrict__ bias, float* __restrict__ out) {
  __shared__ unsigned short lds[16384];    // 2 buf x (A 4096 + B 4096 shorts)
  int id = blockIdx.x + 4 * blockIdx.y + 128 * blockIdx.z;  // flat [0,512)
  int xcd = id & 7, wg = id >> 3;          // wg in [0,64)
  int pair = xcd * 16 + (wg >> 2);         // [0,128) = (n0idx, b)
  int o0 = (wg & 3) * 64;
  int n0 = (pair & 31) * 64;
  int b  = pair >> 5;
  int t  = threadIdx.x;
  int wv = t >> 6, l = t & 63, l15 = l & 15, q = l >> 4;
  int wm = (wv & 1) * 32, wn = (wv >> 1) * 32;
  f32x4 acc[2][2];
#pragma unroll
  for (int i = 0; i < 2; i++)
#pragma unroll
    for (int j = 0; j < 2; j++) acc[i][j] = (f32x4){0.f,0.f,0.f,0.f};
  const unsigned short* Ag = wo + (size_t)o0 * HID;
  const unsigned short* Bg = AO + ((size_t)b * SEQ + n0) * HID;
  int lrow8 = l >> 3, lcol = l & 7;

  auto stage = [&](int kk, int buf) {
    unsigned short* la = lds + buf * 8192;
    unsigned short* lb = la + 4096;
    int k0 = kk * 64;
#pragma unroll
    for (int c0 = 0; c0 < 2; c0++) {       // A+B: 8 chunks each, 2/wave
      int c = wv * 2 + c0;
      int row = c * 8 + lrow8;
      int sg = lcol ^ (row & 7);
      gld16(Ag + (size_t)row * HID + k0 + sg * 8, la + c * 512);
      gld16(Bg + (size_t)row * HID + k0 + sg * 8, lb + c * 512);
    }
  };

  stage(0, 0);
  for (int kk = 0; kk < 8; kk++) {
    int cur = kk & 1;
    WAITVM(0);                             // own stage(kk) loads landed
    barrier_raw();                         // => all waves' stage(kk) landed
    if (kk < 7) stage(kk + 1, cur ^ 1);    // WAR-safe after barrier
    unsigned short* la = lds + cur * 8192;
    unsigned short* lb = la + 4096;
#pragma unroll
    for (int kh = 0; kh < 2; kh++) {
      bf16x8 af[2], bfr[2];
#pragma unroll
      for (int mt = 0; mt < 2; mt++) {
        int row = wm + mt*16 + l15;
        af[mt] = *(const bf16x8*)(la + row*64 + ((kh*4 + q) ^ (row & 7)) * 8);
      }
#pragma unroll
      for (int nt = 0; nt < 2; nt++) {
        int row = wn + nt*16 + l15;
        bfr[nt] = *(const bf16x8*)(lb + row*64 + ((kh*4 + q) ^ (row & 7)) * 8);
      }
#pragma unroll
      for (int mt = 0; mt < 2; mt++)
#pragma unroll
        for (int nt = 0; nt < 2; nt++)
          acc[mt][nt] = __builtin_amdgcn_mfma_f32_16x16x32_bf16(af[mt], bfr[nt], acc[mt][nt], 0,0,0);
    }
  }
#pragma unroll
  for (int mt = 0; mt < 2; mt++)
#pragma unroll
    for (int nt = 0; nt < 2; nt++)
#pragma unroll
      for (int r = 0; r < 4; r++) {
        int o2 = o0 + wm + mt*16 + q*4 + r;
        int n  = n0 + wn + nt*16 + l15;
        out[((size_t)b * DIMC + o2) * SEQ + n] = acc[mt][nt][r] + bias[o2];
      }
}

extern "C" void kernel_launch(void* const* d_in, const int* in_sizes, int n_in,
                              void* d_out, int out_size, void* d_ws, size_t ws_size,
                              hipStream_t stream) {
  const float* x    = (const float*)d_in[0];
  const float* wqkv = (const float*)d_in[1];
  const float* wout = (const float*)d_in[2];
  const float* bout = (const float*)d_in[3];
  float* out = (float*)d_out;
  char* ws = (char*)d_ws;
  unsigned short* wqkv_b = (unsigned short*)(ws);
  unsigned short* wout_b = (unsigned short*)(ws + 786432);
  unsigned short* xT     = (unsigned short*)(ws + 1048576);
  unsigned short* Qs     = (unsigned short*)(ws + 5242880);
  unsigned short* Ks     = (unsigned short*)(ws + 13631488);
  unsigned short* Vt     = (unsigned short*)(ws + 22020096);
  unsigned short* AO     = (unsigned short*)(ws + 30408704);
  prep_kernel<<<1024, 256, 0, stream>>>(x, wqkv, wout, wqkv_b, wout_b, xT);
  qkv_gemm<<<dim3(12, 16, 4), 256, 0, stream>>>(wqkv_b, xT, Qs, Ks, Vt);
  attn_kernel<<<1024, 256, 0, stream>>>(Qs, Ks, Vt, AO);
  out_gemm<<<dim3(4, 32, 4), 256, 0, stream>>>(wout_b, AO, bout, out);
}

// Round 8
// 130.123 us; speedup vs baseline: 1.1122x; 1.1122x over previous
//
#include <hip/hip_runtime.h>
#include <stdint.h>

#define SEQ  2048
#define DIMC 256
#define HID  512
#define NH   8
#define DH   64

typedef __attribute__((ext_vector_type(8))) short bf16x8;
typedef __attribute__((ext_vector_type(4))) float f32x4;
typedef __attribute__((ext_vector_type(16))) float f32x16;
typedef __attribute__((ext_vector_type(2))) unsigned uint2v;
typedef __attribute__((address_space(1))) const uint32_t guint_t;
typedef __attribute__((address_space(3))) uint32_t luint_t;

// async global->LDS, 16B per lane; LDS dest = wave-uniform base + lane*16
__device__ __forceinline__ void gld16(const void* g, void* l) {
  __builtin_amdgcn_global_load_lds((guint_t*)g, (luint_t*)l, 16, 0, 0);
}

// raw barrier: no compiler-inserted vmcnt(0) drain (unlike __syncthreads)
__device__ __forceinline__ void barrier_raw() {
  asm volatile("" ::: "memory");
  __builtin_amdgcn_s_barrier();
  asm volatile("" ::: "memory");
}
#define WAITVM(n) asm volatile("s_waitcnt vmcnt(" #n ")" ::: "memory")

__device__ __forceinline__ unsigned short f2bf(float f) {
  union { float f; uint32_t u; } v; v.f = f;
  return (unsigned short)((v.u + 0x7FFFu + ((v.u >> 16) & 1u)) >> 16);
}

__device__ __forceinline__ uint32_t fbits(float f) {
  union { float f; uint32_t u; } v; v.f = f; return v.u;
}
__device__ __forceinline__ float ffrombits(uint32_t u) {
  union { uint32_t u; float f; } v; v.u = u; return v.f;
}

// pack two fp32 -> (bf16,bf16) dword in ONE instr (RNE)
__device__ __forceinline__ uint32_t cvtpk(float a, float b) {
  uint32_t r;
  asm("v_cvt_pk_bf16_f32 %0, %1, %2" : "=v"(r) : "v"(a), "v"(b));
  return r;
}

// exchange hi 32 lanes of a with lo 32 lanes of b
__device__ __forceinline__ void swap32(uint32_t& a, uint32_t& b) {
#if __has_builtin(__builtin_amdgcn_permlane32_swap)
  uint2v r = __builtin_amdgcn_permlane32_swap(a, b, false, false);
  a = r[0]; b = r[1];
#else
  uint32_t aw = __shfl_xor(a, 32);
  uint32_t bw = __shfl_xor(b, 32);
  bool lo = (threadIdx.x & 32) == 0;
  uint32_t an = lo ? a : bw;
  uint32_t bn = lo ? aw : b;
  a = an; b = bn;
#endif
}

// ---------------------------------------------------------------------------
// prep: w_qkv -> bf16 (Q rows pre-scaled by SCALE*log2e), w_out -> bf16,
//       x [b][i][n] fp32 -> xT [b][n][i] bf16
// ---------------------------------------------------------------------------
__global__ __launch_bounds__(256) void prep_kernel(
    const float* __restrict__ x, const float* __restrict__ wqkv,
    const float* __restrict__ wout,
    unsigned short* __restrict__ wqkv_b, unsigned short* __restrict__ wout_b,
    unsigned short* __restrict__ xT) {
  __shared__ float tile[64][65];
  int blk = blockIdx.x;
  int t = threadIdx.x;
  if (blk < 384) {
    int idx = blk * 1024 + t * 4;
    float4 v = *(const float4*)(wqkv + idx);
    float s = ((idx >> 8) < HID) ? 0.18033688011112042f : 1.0f;  // 0.125*log2(e)
    ushort4 o;
    o.x = f2bf(v.x * s); o.y = f2bf(v.y * s);
    o.z = f2bf(v.z * s); o.w = f2bf(v.w * s);
    *(ushort4*)(wqkv_b + idx) = o;
    return;
  }
  if (blk < 512) {
    int idx = (blk - 384) * 1024 + t * 4;
    float4 v = *(const float4*)(wout + idx);
    ushort4 o;
    o.x = f2bf(v.x); o.y = f2bf(v.y); o.z = f2bf(v.z); o.w = f2bf(v.w);
    *(ushort4*)(wout_b + idx) = o;
    return;
  }
  int tid = blk - 512;
  int b  = tid >> 7;
  int r  = tid & 127;
  int i0 = (r >> 5) * 64;
  int n0 = (r & 31) * 64;
  const float* xb = x + (size_t)b * DIMC * SEQ;
  int tn = t & 15, ti = t >> 4;
#pragma unroll
  for (int j = 0; j < 4; j++) {
    int il = ti + j * 16;
    float4 v = *(const float4*)(xb + (size_t)(i0 + il) * SEQ + n0 + tn * 4);
    tile[il][tn*4+0] = v.x; tile[il][tn*4+1] = v.y;
    tile[il][tn*4+2] = v.z; tile[il][tn*4+3] = v.w;
  }
  __syncthreads();
  unsigned short* xTb = xT + (size_t)b * SEQ * DIMC;
#pragma unroll
  for (int j = 0; j < 4; j++) {
    int nl = ti + j * 16;
    int i4 = tn * 4;
    uint2 pk;
    pk.x = (uint32_t)f2bf(tile[i4+0][nl]) | ((uint32_t)f2bf(tile[i4+1][nl]) << 16);
    pk.y = (uint32_t)f2bf(tile[i4+2][nl]) | ((uint32_t)f2bf(tile[i4+3][nl]) << 16);
    *(uint2*)(xTb + (size_t)(n0 + nl) * DIMC + i0 + i4) = pk;
  }
}

// ---------------------------------------------------------------------------
// qkv_gemm: [1536,256]x[256,2048] per batch, 128x128 tile, BK=64.
// XCD-pinned swizzle; double-buffered gld16; one barrier/K-step.
// ---------------------------------------------------------------------------
__global__ __launch_bounds__(256, 3) void qkv_gemm(
    const unsigned short* __restrict__ wq, const unsigned short* __restrict__ xT,
    unsigned short* __restrict__ Qs, unsigned short* __restrict__ Ks,
    unsigned short* __restrict__ Vt) {
  __shared__ unsigned short lds[32768];
  int id = blockIdx.x + 12 * blockIdx.y + 192 * blockIdx.z;  // flat [0,768)
  int xcd = id & 7, wg = id >> 3;          // wg in [0,96)
  int pair = xcd * 8 + wg / 12;            // [0,64) = (n0idx, b)
  int o0 = (wg % 12) * 128;
  int n0 = (pair & 15) * 128;
  int b  = pair >> 4;
  int t  = threadIdx.x;
  int wv = t >> 6, l = t & 63, l15 = l & 15, q = l >> 4;
  int wm = (wv & 1) * 64, wn = (wv >> 1) * 64;
  f32x4 acc[4][4];
#pragma unroll
  for (int i = 0; i < 4; i++)
#pragma unroll
    for (int j = 0; j < 4; j++) acc[i][j] = (f32x4){0.f, 0.f, 0.f, 0.f};
  const unsigned short* Ag = wq + (size_t)o0 * DIMC;
  const unsigned short* Bg = xT + ((size_t)b * SEQ + n0) * DIMC;
  int lrow8 = l >> 3, lcol = l & 7;

  auto stage = [&](int kk, int buf) {
    unsigned short* la = lds + (buf << 14);
    unsigned short* lb = la + 8192;
    int k0 = kk * 64;
#pragma unroll
    for (int c0 = 0; c0 < 4; c0++) {
      int c = wv * 4 + c0;
      int row = c * 8 + lrow8;
      int sg = lcol ^ (row & 7);
      gld16(Ag + (size_t)row * DIMC + k0 + sg * 8, la + c * 512);
      gld16(Bg + (size_t)row * DIMC + k0 + sg * 8, lb + c * 512);
    }
  };

  stage(0, 0);
  for (int kk = 0; kk < 4; kk++) {
    int cur = kk & 1;
    WAITVM(0);                             // own stage(kk) loads landed
    barrier_raw();                         // => all waves' stage(kk) landed
    if (kk < 3) stage(kk + 1, cur ^ 1);    // WAR-safe after barrier
    unsigned short* la = lds + (cur << 14);
    unsigned short* lb = la + 8192;
#pragma unroll
    for (int kh = 0; kh < 2; kh++) {
      bf16x8 af[4], bfr[4];
#pragma unroll
      for (int mt = 0; mt < 4; mt++) {
        int row = wm + mt*16 + l15;
        af[mt] = *(const bf16x8*)(la + row*64 + ((kh*4 + q) ^ (row & 7)) * 8);
      }
#pragma unroll
      for (int nt = 0; nt < 4; nt++) {
        int row = wn + nt*16 + l15;
        bfr[nt] = *(const bf16x8*)(lb + row*64 + ((kh*4 + q) ^ (row & 7)) * 8);
      }
#pragma unroll
      for (int mt = 0; mt < 4; mt++)
#pragma unroll
        for (int nt = 0; nt < 4; nt++)
          acc[mt][nt] = __builtin_amdgcn_mfma_f32_16x16x32_bf16(af[mt], bfr[nt], acc[mt][nt], 0, 0, 0);
    }
  }
  barrier_raw();                 // all waves done with LDS buffers before reuse
  int seg3 = o0 >> 9;            // 0=Q, 1=K, 2=V
  int h0   = (o0 & 511) >> 6;
  if (seg3 == 2) {
    // V: transpose via LDS [ol][nn] -> 16B n-contiguous stores
#pragma unroll
    for (int mt = 0; mt < 4; mt++)
#pragma unroll
      for (int nt = 0; nt < 4; nt++)
#pragma unroll
        for (int r = 0; r < 4; r++) {
          int ol = wm + mt * 16 + q * 4 + r;
          int nn = wn + nt * 16 + l15;
          lds[ol * 136 + nn] = f2bf(acc[mt][nt][r]);
        }
    __syncthreads();
#pragma unroll
    for (int i = 0; i < 8; i++) {
      int idx = i * 256 + t;
      int ol  = idx >> 4;
      int nnb = (idx & 15) * 8;
      uint4 v = *(const uint4*)(lds + ol * 136 + nnb);
      int h = h0 + (ol >> 6), d = ol & 63;
      *(uint4*)(Vt + (((size_t)b * NH + h) * DH + d) * SEQ + n0 + nnb) = v;
    }
  } else {
    unsigned short* dst = (seg3 == 0) ? Qs : Ks;
#pragma unroll
    for (int mt = 0; mt < 4; mt++)
#pragma unroll
      for (int nt = 0; nt < 4; nt++)
#pragma unroll
        for (int r = 0; r < 4; r++) {
          int ol = wm + mt * 16 + q * 4 + r;
          int nn = wn + nt * 16 + l15;
          lds[nn * 136 + ol] = f2bf(acc[mt][nt][r]);
        }
    __syncthreads();
#pragma unroll
    for (int i = 0; i < 8; i++) {
      int idx = i * 256 + t;
      int nn  = idx >> 4;
      int olb = (idx & 15) * 8;
      uint4 v = *(const uint4*)(lds + nn * 136 + olb);
      int h = h0 + (olb >> 6), d = olb & 63;
      *(uint4*)(dst + (((size_t)b * NH + h) * SEQ + n0 + nn) * DH + d) = v;
    }
  }
}

// ---------------------------------------------------------------------------
// attn: 8-wave blocks (512 thr), q-tile 128, kv-split-2. Grid 512 XCD-pinned
// blocks = 2 blocks/CU x 8 waves = SAME 16 waves/CU as r5 (TLP is king: r7
// showed 8 waves/CU = 70us vs 16 = 51us), but barrier EVENTS per CU halve
// (2x32 vs 4x32) while work per event doubles (128 q/iter) -> stall fraction
// drops. Per-wave body, swizzles, staging scheme identical to r5 (proven).
// LDS 32KB staging; epilogue reuses it as the [128q][64d] fp32 combine.
// ---------------------------------------------------------------------------
__global__ __launch_bounds__(512, 4) void attn_kernel(
    const unsigned short* __restrict__ Qs, const unsigned short* __restrict__ Ks,
    const unsigned short* __restrict__ Vt, unsigned short* __restrict__ AO) {
  __shared__ unsigned short KVs[16384];  // 2 buf x (K[2][32][64] | Vpair[2][32][64]) = 32KB
  __shared__ float Lc[256];              // [cg][128 q] row-sum partials
  // XCD swizzle: id&7 = XCD slot; 4 bh x 16 q-tiles per XCD -> K/V L2-resident
  int id = blockIdx.x;
  int s  = id >> 3;                      // [0,64)
  int bh = (id & 7) * 4 + (s & 3);
  int q0 = (s >> 2) * 128;
  int b = bh >> 3, h = bh & 7;
  int t = threadIdx.x;
  int w = t >> 6, l = t & 63, l31 = l & 31, lh = l >> 5;
  int cg = w & 1, qg = w >> 1;           // qg in [0,4)
  // Q B-frags (n=query=l31, k=head-dim) straight from global, once
  const unsigned short* Qg = Qs + ((size_t)bh * SEQ + q0 + qg * 32) * DH;
  bf16x8 qb[4];
#pragma unroll
  for (int kc = 0; kc < 4; kc++)
    qb[kc] = *(const bf16x8*)(Qg + l31 * DH + kc*16 + lh*8);
  f32x16 oacc[2];
  float lsum = 0.f;
#pragma unroll
  for (int dt = 0; dt < 2; dt++)
#pragma unroll
    for (int r = 0; r < 16; r++) oacc[dt][r] = 0.f;

  // staging roles: tile = w>>1 (0=K.cg0, 1=K.cg1, 2=V.cg0, 3=V.cg1),
  // half = w&1 (2 waves per tile, 2 gld16 per wave per iter)
  int which = w >> 1, half = w & 1;
  const unsigned short* sgp[2];
  unsigned short* dst0;
  size_t step;
  if (which < 2) {                       // K tile for chunk 'which'
    const unsigned short* Ksrc = Ks + ((size_t)bh * SEQ + which * 1024) * DH;
#pragma unroll
    for (int gi = 0; gi < 2; gi++) {
      int g = half * 2 + gi;
      int kr = g * 8 + (l >> 3);
      sgp[gi] = Ksrc + (size_t)kr * DH + ((l & 7) ^ (kr & 7)) * 8;
    }
    dst0 = (unsigned short*)KVs + which * 2048 + half * 1024;
    step = (size_t)32 * DH;
  } else {                               // V tile chunk 'which-2' (paired-row)
    const unsigned short* Vsrc = Vt + (size_t)bh * DH * SEQ + (which - 2) * 1024;
#pragma unroll
    for (int gi = 0; gi < 2; gi++) {
      int g = half * 2 + gi;
      int r = g * 8 + (l >> 3);
      int u = (l & 7) ^ (r & 7);
      int d = (u >> 2) * 32 + r;
      int j = u & 3;
      sgp[gi] = Vsrc + (size_t)d * SEQ + j * 8;
    }
    dst0 = (unsigned short*)KVs + 4096 + (which - 2) * 2048 + half * 1024;
    step = 32;
  }

  auto stage = [&](int it2, int buf) {
    size_t off = (size_t)it2 * step;
    unsigned short* dstb = dst0 + buf * 8192;
    gld16(sgp[0] + off, dstb);
    gld16(sgp[1] + off, dstb + 512);
  };

  stage(0, 0);
  for (int it = 0; it < 32; it++) {
    int cur = it & 1;
    WAITVM(0);                             // own stage(it) loads landed
    barrier_raw();                         // => all waves' stage(it) landed
    if (it < 31) stage(it + 1, cur ^ 1);   // WAR-safe after barrier
    const unsigned short* Kst = KVs + cur * 8192 + cg * 2048;
    const unsigned short* Vst = KVs + cur * 8192 + 4096 + cg * 2048;
    // S^T = K Q^T : A = K (m=key 32), B = Q (n=query 32)
    f32x16 st;
#pragma unroll
    for (int r = 0; r < 16; r++) st[r] = 0.f;
    __builtin_amdgcn_s_setprio(1);
#pragma unroll
    for (int kc = 0; kc < 4; kc++) {
      bf16x8 kf = *(const bf16x8*)(Kst + l31 * 64 + ((kc*2 + lh) ^ (l31 & 7)) * 8);
      st = __builtin_amdgcn_mfma_f32_32x32x16_bf16(kf, qb[kc], st, 0, 0, 0);
    }
    __builtin_amdgcn_s_setprio(0);
    // V B-frags (n=d, k=key 32) from paired-row tile
    bf16x8 vf[2][2];
#pragma unroll
    for (int kc2 = 0; kc2 < 2; kc2++)
#pragma unroll
      for (int dt = 0; dt < 2; dt++)
        vf[kc2][dt] = *(const bf16x8*)(Vst + l31 * 64 +
                                       ((dt*4 + kc2*2 + lh) ^ (l31 & 7)) * 8);
    // p = exp2(s); pairwise tree row-sum
    float p[16];
#pragma unroll
    for (int r = 0; r < 16; r++) p[r] = __builtin_amdgcn_exp2f(st[r]);
    {
      float t0=p[0]+p[1],  t1=p[2]+p[3],  t2=p[4]+p[5],   t3=p[6]+p[7];
      float t4=p[8]+p[9],  t5=p[10]+p[11], t6=p[12]+p[13], t7=p[14]+p[15];
      lsum += ((t0+t1)+(t2+t3)) + ((t4+t5)+(t6+t7));
    }
    // D-layout -> A-layout in registers (permlane32_swap + cvt_pk_bf16)
    bf16x8 af[2];
#pragma unroll
    for (int hf = 0; hf < 2; hf++) {
      uint32_t xs[4], ys[4];
#pragma unroll
      for (int j = 0; j < 4; j++) {
        xs[j] = fbits(p[hf*8 + j]);
        ys[j] = fbits(p[hf*8 + 4 + j]);
        swap32(xs[j], ys[j]);
      }
      union { uint32_t u[4]; bf16x8 v; } cv;
      cv.u[0] = cvtpk(ffrombits(xs[0]), ffrombits(xs[1]));
      cv.u[1] = cvtpk(ffrombits(xs[2]), ffrombits(xs[3]));
      cv.u[2] = cvtpk(ffrombits(ys[0]), ffrombits(ys[1]));
      cv.u[3] = cvtpk(ffrombits(ys[2]), ffrombits(ys[3]));
      af[hf] = cv.v;
    }
    __builtin_amdgcn_s_setprio(1);
#pragma unroll
    for (int kc2 = 0; kc2 < 2; kc2++)
#pragma unroll
      for (int dt = 0; dt < 2; dt++)
        oacc[dt] = __builtin_amdgcn_mfma_f32_32x32x16_bf16(af[kc2], vf[kc2][dt], oacc[dt], 0, 0, 0);
    __builtin_amdgcn_s_setprio(0);
  }
  // ---- combine the two kv-chunks (purely additive; no max-rescale) ----
  {
    float v = lsum;
    v += __shfl_xor(v, 32);                // lo/hi halves hold disjoint keys
    if (l < 32) Lc[cg * 128 + qg * 32 + l31] = v;
  }
  __syncthreads();
  float* Oc = (float*)KVs;                 // [128 q][64 d] fp32 = 32 KB
  if (cg == 1) {
#pragma unroll
    for (int dt = 0; dt < 2; dt++)
#pragma unroll
      for (int r = 0; r < 16; r++) {
        int qrow = qg*32 + (r & 3) + 8*(r >> 2) + 4*lh;
        Oc[qrow * 64 + dt*32 + l31] = oacc[dt][r];
      }
  }
  __syncthreads();
  if (cg == 0) {
    unsigned short* AOb = AO + (size_t)b * SEQ * HID + h * DH;
#pragma unroll
    for (int r = 0; r < 16; r++) {
      int qrow = qg*32 + (r & 3) + 8*(r >> 2) + 4*lh;
      float inv = __builtin_amdgcn_rcpf(Lc[qrow] + Lc[128 + qrow]);
      int n = q0 + qrow;
#pragma unroll
      for (int dt = 0; dt < 2; dt++) {
        float val = (oacc[dt][r] + Oc[qrow * 64 + dt*32 + l31]) * inv;
        AOb[(size_t)n * HID + dt*32 + l31] = f2bf(val);
      }
    }
  }
}

// ---------------------------------------------------------------------------
// out_gemm: [256,512] x AO^T -> out[b][256][2048] fp32 + bias, 64x64 tile.
// XCD-pinned swizzle; double-buffered gld16; one barrier/K-step.
// ---------------------------------------------------------------------------
__global__ __launch_bounds__(256, 2) void out_gemm(
    const unsigned short* __restrict__ wo, const unsigned short* __restrict__ AO,
    const float* __restrict__ bias, float* __restrict__ out) {
  __shared__ unsigned short lds[16384];    // 2 buf x (A 4096 + B 4096 shorts)
  int id = blockIdx.x + 4 * blockIdx.y + 128 * blockIdx.z;  // flat [0,512)
  int xcd = id & 7, wg = id >> 3;          // wg in [0,64)
  int pair = xcd * 16 + (wg >> 2);         // [0,128) = (n0idx, b)
  int o0 = (wg & 3) * 64;
  int n0 = (pair & 31) * 64;
  int b  = pair >> 5;
  int t  = threadIdx.x;
  int wv = t >> 6, l = t & 63, l15 = l & 15, q = l >> 4;
  int wm = (wv & 1) * 32, wn = (wv >> 1) * 32;
  f32x4 acc[2][2];
#pragma unroll
  for (int i = 0; i < 2; i++)
#pragma unroll
    for (int j = 0; j < 2; j++) acc[i][j] = (f32x4){0.f,0.f,0.f,0.f};
  const unsigned short* Ag = wo + (size_t)o0 * HID;
  const unsigned short* Bg = AO + ((size_t)b * SEQ + n0) * HID;
  int lrow8 = l >> 3, lcol = l & 7;

  auto stage = [&](int kk, int buf) {
    unsigned short* la = lds + buf * 8192;
    unsigned short* lb = la + 4096;
    int k0 = kk * 64;
#pragma unroll
    for (int c0 = 0; c0 < 2; c0++) {       // A+B: 8 chunks each, 2/wave
      int c = wv * 2 + c0;
      int row = c * 8 + lrow8;
      int sg = lcol ^ (row & 7);
      gld16(Ag + (size_t)row * HID + k0 + sg * 8, la + c * 512);
      gld16(Bg + (size_t)row * HID + k0 + sg * 8, lb + c * 512);
    }
  };

  stage(0, 0);
  for (int kk = 0; kk < 8; kk++) {
    int cur = kk & 1;
    WAITVM(0);                             // own stage(kk) loads landed
    barrier_raw();                         // => all waves' stage(kk) landed
    if (kk < 7) stage(kk + 1, cur ^ 1);    // WAR-safe after barrier
    unsigned short* la = lds + cur * 8192;
    unsigned short* lb = la + 4096;
#pragma unroll
    for (int kh = 0; kh < 2; kh++) {
      bf16x8 af[2], bfr[2];
#pragma unroll
      for (int mt = 0; mt < 2; mt++) {
        int row = wm + mt*16 + l15;
        af[mt] = *(const bf16x8*)(la + row*64 + ((kh*4 + q) ^ (row & 7)) * 8);
      }
#pragma unroll
      for (int nt = 0; nt < 2; nt++) {
        int row = wn + nt*16 + l15;
        bfr[nt] = *(const bf16x8*)(lb + row*64 + ((kh*4 + q) ^ (row & 7)) * 8);
      }
#pragma unroll
      for (int mt = 0; mt < 2; mt++)
#pragma unroll
        for (int nt = 0; nt < 2; nt++)
          acc[mt][nt] = __builtin_amdgcn_mfma_f32_16x16x32_bf16(af[mt], bfr[nt], acc[mt][nt], 0,0,0);
    }
  }
#pragma unroll
  for (int mt = 0; mt < 2; mt++)
#pragma unroll
    for (int nt = 0; nt < 2; nt++)
#pragma unroll
      for (int r = 0; r < 4; r++) {
        int o2 = o0 + wm + mt*16 + q*4 + r;
        int n  = n0 + wn + nt*16 + l15;
        out[((size_t)b * DIMC + o2) * SEQ + n] = acc[mt][nt][r] + bias[o2];
      }
}

extern "C" void kernel_launch(void* const* d_in, const int* in_sizes, int n_in,
                              void* d_out, int out_size, void* d_ws, size_t ws_size,
                              hipStream_t stream) {
  const float* x    = (const float*)d_in[0];
  const float* wqkv = (const float*)d_in[1];
  const float* wout = (const float*)d_in[2];
  const float* bout = (const float*)d_in[3];
  float* out = (float*)d_out;
  char* ws = (char*)d_ws;
  unsigned short* wqkv_b = (unsigned short*)(ws);
  unsigned short* wout_b = (unsigned short*)(ws + 786432);
  unsigned short* xT     = (unsigned short*)(ws + 1048576);
  unsigned short* Qs     = (unsigned short*)(ws + 5242880);
  unsigned short* Ks     = (unsigned short*)(ws + 13631488);
  unsigned short* Vt     = (unsigned short*)(ws + 22020096);
  unsigned short* AO     = (unsigned short*)(ws + 30408704);
  prep_kernel<<<1024, 256, 0, stream>>>(x, wqkv, wout, wqkv_b, wout_b, xT);
  qkv_gemm<<<dim3(12, 16, 4), 256, 0, stream>>>(wqkv_b, xT, Qs, Ks, Vt);
  attn_kernel<<<512, 512, 0, stream>>>(Qs, Ks, Vt, AO);
  out_gemm<<<dim3(4, 32, 4), 256, 0, stream>>>(wout_b, AO, bout, out);
}